// Round 3
// baseline (350.188 us; speedup 1.0000x reference)
//
#include <hip/hip_runtime.h>
#include <hip/hip_bf16.h>
#include <stdint.h>

#define M_DIM 8192
#define N_DIM 4096
#define K_DIM 4096

typedef __attribute__((ext_vector_type(8))) __bf16 bf16x8;
typedef __attribute__((ext_vector_type(16))) float f32x16;

__device__ inline unsigned short f2bf(float f) {
  unsigned u = __builtin_bit_cast(unsigned, f);
  u += 0x7FFF + ((u >> 16) & 1);   // round-to-nearest-even
  return (unsigned short)(u >> 16);
}

__device__ inline void async_copy16(const void* g, void* l) {
  __builtin_amdgcn_global_load_lds(
      (const __attribute__((address_space(1))) unsigned int*)g,
      (__attribute__((address_space(3))) unsigned int*)l, 16, 0, 0);
}

// ---------- fused prep: blocks [0,4096) build W_eff; [4096,6144) cvt x ----------
__global__ __launch_bounds__(256) void prep_kernel(
    const float* __restrict__ x, unsigned short* __restrict__ xb,
    const int* __restrict__ Wq, const float* __restrict__ scale,
    const float* __restrict__ zero, const float* __restrict__ A,
    const float* __restrict__ Bm, unsigned short* __restrict__ Weff) {
  int t = threadIdx.x;
  if (blockIdx.x < 4096) {
    __shared__ float sA[64 * 17];
    __shared__ float sB[16 * 64];
    int bo = blockIdx.x >> 6;
    int bi = blockIdx.x & 63;
    int o0 = bo * 64, i0 = bi * 64;
    for (int j = t; j < 1024; j += 256) sA[(j >> 4) * 17 + (j & 15)] = A[i0 * 16 + j];
    for (int j = t; j < 1024; j += 256) sB[j] = Bm[(j >> 6) * N_DIM + o0 + (j & 63)];
    __syncthreads();
    for (int e = 0; e < 16; ++e) {
      int idx = e * 256 + t;
      int oo = idx >> 6, ii = idx & 63;
      int o = o0 + oo;
      float sc = scale[o * 64 + bi];
      float zp = zero[o * 64 + bi];
      float w = ((float)Wq[(size_t)o * K_DIM + i0 + ii] - zp) * sc;
      float acc = 0.f;
#pragma unroll
      for (int r = 0; r < 16; ++r) acc += sA[ii * 17 + r] * sB[r * 64 + oo];
      w += 2.0f * acc;
      Weff[(size_t)o * K_DIM + i0 + ii] = f2bf(w);
    }
  } else {
    int i = (blockIdx.x - 4096) * 256 + t;
    int stride = 2048 * 256;
    int n4 = (M_DIM * K_DIM) / 4;
    for (; i < n4; i += stride) {
      float4 v = reinterpret_cast<const float4*>(x)[i];
      ushort4 o;
      o.x = f2bf(v.x); o.y = f2bf(v.y); o.z = f2bf(v.z); o.w = f2bf(v.w);
      reinterpret_cast<ushort4*>(xb)[i] = o;
    }
  }
}

// ---------- 256x256 8-phase bf16 GEMM, 32x32x16 MFMA ----------
#define BAR() __builtin_amdgcn_s_barrier()
#define SB()  __builtin_amdgcn_sched_barrier(0)
#define WAIT_LGKM() do { asm volatile("s_waitcnt lgkmcnt(0)" ::: "memory"); SB(); } while (0)
#define WAIT_VM6()  do { asm volatile("s_waitcnt vmcnt(6)" ::: "memory"); } while (0)

__device__ __forceinline__ bf16x8 lds_frag(const unsigned short* region, int row, int c) {
  return *reinterpret_cast<const bf16x8*>(region + row * 64 + ((c ^ (row & 7)) << 3));
}

// A: within wave's 128-row region, half mh: rows mh*64 + rt*32 + (l&31); k-slice ks:
// 16B chunk = ks*2 + (l>>5)
__device__ __forceinline__ void readA32(const unsigned short* reg, int mh, int lane,
                                        bf16x8 a[2][4]) {
  int r = lane & 31, hi = lane >> 5;
#pragma unroll
  for (int rt = 0; rt < 2; ++rt) {
    int row = mh * 64 + rt * 32 + r;
#pragma unroll
    for (int ks = 0; ks < 4; ++ks) a[rt][ks] = lds_frag(reg, row, ks * 2 + hi);
  }
}

__device__ __forceinline__ void readB32(const unsigned short* reg, int rB, int nh, int lane,
                                        bf16x8 b[4]) {
  int r = lane & 31, hi = lane >> 5;
  int row = rB + nh * 32 + r;
#pragma unroll
  for (int ks = 0; ks < 4; ++ks) b[ks] = lds_frag(reg, row, ks * 2 + hi);
}

__device__ __forceinline__ void mfma_phase32(const bf16x8 a[2][4], const bf16x8 b[4],
                                             f32x16 acc[4][2], int mh, int nh) {
  __builtin_amdgcn_s_setprio(1);
#pragma unroll
  for (int ks = 0; ks < 4; ++ks)
#pragma unroll
    for (int rt = 0; rt < 2; ++rt)
      acc[mh * 2 + rt][nh] = __builtin_amdgcn_mfma_f32_32x32x16_bf16(
          a[rt][ks], b[ks], acc[mh * 2 + rt][nh], 0, 0, 0);
  __builtin_amdgcn_s_setprio(0);
}

__global__ __launch_bounds__(512, 2) void gemm_kernel(
    const unsigned short* __restrict__ xb, const unsigned short* __restrict__ wb,
    const float* __restrict__ bias, float* __restrict__ out) {
  // LDS: 2 bufs x [A0|A1|B0|B1], each region 128x64 bf16 (8192 ushort) = 128 KiB
  __shared__ unsigned short lds[65536];

  int bid = blockIdx.x;
  int swz = (bid & 7) * 64 + (bid >> 3);   // bijective: 512 % 8 == 0
  int mt = swz >> 4, nt = swz & 15;
  int m0 = mt * 256, n0 = nt * 256;

  int tid = threadIdx.x;
  int w = tid >> 6, lane = tid & 63;
  int wr = w >> 2, wc = w & 3;             // 2 x 4 waves; per-wave out = 128 x 64
  int rB = (wc & 1) * 64;

  // staging: chunk = l*512 + tid (16B units), row = chunk>>3, phys col = chunk&7,
  // logical (global) col = (chunk&7) ^ (row&7)  [inverse-swizzled source, linear dest]
  int r0 = tid >> 3, c0g = (tid & 7) ^ (r0 & 7);
  int ch1 = 512 + tid;
  int r1 = ch1 >> 3, c1g = (ch1 & 7) ^ (r1 & 7);
  int co0 = tid * 8, co1 = ch1 * 8;

  const unsigned short* sA[2][2];
  const unsigned short* sB[2][2];
  sA[0][0] = xb + (size_t)(m0 + r0) * K_DIM + c0g * 8;
  sA[0][1] = xb + (size_t)(m0 + r1) * K_DIM + c1g * 8;
  sA[1][0] = xb + (size_t)(m0 + 128 + r0) * K_DIM + c0g * 8;
  sA[1][1] = xb + (size_t)(m0 + 128 + r1) * K_DIM + c1g * 8;
  sB[0][0] = wb + (size_t)(n0 + r0) * K_DIM + c0g * 8;
  sB[0][1] = wb + (size_t)(n0 + r1) * K_DIM + c1g * 8;
  sB[1][0] = wb + (size_t)(n0 + 128 + r0) * K_DIM + c0g * 8;
  sB[1][1] = wb + (size_t)(n0 + 128 + r1) * K_DIM + c1g * 8;

#define STAGE_A(h, buf, kt) do { \
    async_copy16(sA[h][0] + (kt), &lds[(buf) * 32768 + (h) * 8192 + co0]); \
    async_copy16(sA[h][1] + (kt), &lds[(buf) * 32768 + (h) * 8192 + co1]); } while (0)
#define STAGE_B(h, buf, kt) do { \
    async_copy16(sB[h][0] + (kt), &lds[(buf) * 32768 + 16384 + (h) * 8192 + co0]); \
    async_copy16(sB[h][1] + (kt), &lds[(buf) * 32768 + 16384 + (h) * 8192 + co1]); } while (0)

  const unsigned short* aR[2] = { &lds[wr * 8192], &lds[32768 + wr * 8192] };
  const unsigned short* bR[2] = { &lds[16384 + (wc >> 1) * 8192],
                                  &lds[32768 + 16384 + (wc >> 1) * 8192] };

  f32x16 acc[4][2];
#pragma unroll
  for (int i = 0; i < 4; ++i)
#pragma unroll
    for (int j = 0; j < 2; ++j) acc[i][j] = (f32x16)(0.f);

  // prologue: tile0 full, then tile1's B0,B1,A0 (A1 comes at P1)
  STAGE_A(0, 0, 0); STAGE_B(0, 0, 0); STAGE_B(1, 0, 0); STAGE_A(1, 0, 0);
  STAGE_B(0, 1, 64); STAGE_B(1, 1, 64); STAGE_A(0, 1, 64);
  WAIT_VM6(); BAR(); SB();   // oldest 8 loads (= tile0) landed

  bf16x8 a[2][4], b0[4], b1[4];

#pragma unroll 1
  for (int i = 0; i < 32; ++i) {
    int k1 = (2 * i + 1) * 64;             // tile t+1 (never wraps)
    int k2 = ((2 * i + 2) & 63) * 64;      // tile t+2 (wrap harmless at tail)
    int k3 = ((2 * i + 3) & 63) * 64;      // tile t+3

    // P1: Q(0,0) of tile t         stage Ah1(t+1)->buf1 (freed prev-P7)
    readA32(aR[0], 0, lane, a); readB32(bR[0], rB, 0, lane, b0);
    STAGE_A(1, 1, k1);
    SB(); BAR(); WAIT_LGKM();
    mfma_phase32(a, b0, acc, 0, 0);
    SB(); BAR(); SB();
    // P2: Q(0,1)
    readB32(bR[0], rB, 1, lane, b1);
    SB(); BAR(); WAIT_LGKM();
    mfma_phase32(a, b1, acc, 0, 1);
    SB(); BAR(); SB();
    // P3: Q(1,1)                   stage Bh0(t+2)->buf0 (B freed after P2)
    readA32(aR[0], 1, lane, a);
    STAGE_B(0, 0, k2);
    SB(); BAR(); WAIT_LGKM();
    mfma_phase32(a, b1, acc, 1, 1);
    SB(); BAR(); SB();
    // P4: Q(1,0)                   stage Bh1,Ah0(t+2)->buf0 (A freed after P3)
    STAGE_B(1, 0, k2); STAGE_A(0, 0, k2);
    SB(); BAR();
    mfma_phase32(a, b0, acc, 1, 0);
    SB(); WAIT_VM6(); BAR(); SB();   // full tile t+1 landed; 3 halves in flight
    // P5: Q(0,0) of tile t+1       stage Ah1(t+2)->buf0
    readA32(aR[1], 0, lane, a); readB32(bR[1], rB, 0, lane, b0);
    STAGE_A(1, 0, k2);
    SB(); BAR(); WAIT_LGKM();
    mfma_phase32(a, b0, acc, 0, 0);
    SB(); BAR(); SB();
    // P6: Q(0,1)
    readB32(bR[1], rB, 1, lane, b1);
    SB(); BAR(); WAIT_LGKM();
    mfma_phase32(a, b1, acc, 0, 1);
    SB(); BAR(); SB();
    // P7: Q(1,1)                   stage Bh0(t+3)->buf1 (B freed after P6)
    readA32(aR[1], 1, lane, a);
    STAGE_B(0, 1, k3);
    SB(); BAR(); WAIT_LGKM();
    mfma_phase32(a, b1, acc, 1, 1);
    SB(); BAR(); SB();
    // P8: Q(1,0)                   stage Bh1,Ah0(t+3)->buf1 (A freed after P7)
    STAGE_B(1, 1, k3); STAGE_A(0, 1, k3);
    SB(); BAR();
    mfma_phase32(a, b0, acc, 1, 0);
    SB(); WAIT_VM6(); BAR(); SB();   // full tile t+2 landed; 3 halves in flight
  }
  asm volatile("s_waitcnt vmcnt(0)" ::: "memory");  // drain stray tail prefetches

  // epilogue: 32x32 C/D layout col=lane&31, row=(reg&3)+8*(reg>>2)+4*(lane>>5)
  int col = lane & 31, hi = lane >> 5;
#pragma unroll
  for (int ni = 0; ni < 2; ++ni) {
    int n = n0 + wc * 64 + ni * 32 + col;
    float bv = bias[n];
#pragma unroll
    for (int mi = 0; mi < 4; ++mi) {
      int mbase = m0 + wr * 128 + mi * 32 + 4 * hi;
#pragma unroll
      for (int r = 0; r < 16; ++r) {
        int m = mbase + (r & 3) + 8 * (r >> 2);
        out[(size_t)m * N_DIM + n] = acc[mi][ni][r] + bv;
      }
    }
  }
#undef STAGE_A
#undef STAGE_B
}

extern "C" void kernel_launch(void* const* d_in, const int* in_sizes, int n_in,
                              void* d_out, int out_size, void* d_ws, size_t ws_size,
                              hipStream_t stream) {
  const float* x     = (const float*)d_in[0];
  const int*   Wq    = (const int*)d_in[1];
  const float* scale = (const float*)d_in[2];
  const float* zero  = (const float*)d_in[3];
  const float* lA    = (const float*)d_in[4];
  const float* lB    = (const float*)d_in[5];
  const float* bias  = (const float*)d_in[6];
  float* out = (float*)d_out;

  unsigned short* xb = (unsigned short*)d_ws;                                      // 64 MB
  unsigned short* wb = (unsigned short*)((char*)d_ws + (size_t)M_DIM * K_DIM * 2); // +32 MB

  prep_kernel<<<6144, 256, 0, stream>>>(x, xb, Wq, scale, zero, lA, lB, wb);
  gemm_kernel<<<512, 512, 0, stream>>>(xb, wb, bias, out);
}

// Round 4
// 319.811 us; speedup vs baseline: 1.0950x; 1.0950x over previous
//
#include <hip/hip_runtime.h>
#include <hip/hip_bf16.h>
#include <stdint.h>

#define M_DIM 8192
#define N_DIM 4096
#define K_DIM 4096

typedef __attribute__((ext_vector_type(8))) __bf16 bf16x8;
typedef __attribute__((ext_vector_type(4))) float f32x4;

__device__ inline unsigned short f2bf(float f) {
  unsigned u = __builtin_bit_cast(unsigned, f);
  u += 0x7FFF + ((u >> 16) & 1);   // round-to-nearest-even
  return (unsigned short)(u >> 16);
}

__device__ inline void async_copy16(const void* g, void* l) {
  __builtin_amdgcn_global_load_lds(
      (const __attribute__((address_space(1))) unsigned int*)g,
      (__attribute__((address_space(3))) unsigned int*)l, 16, 0, 0);
}

// ---------- fused prep: blocks [0,4096) build W_eff; [4096,6144) cvt x ----------
__global__ __launch_bounds__(256) void prep_kernel(
    const float* __restrict__ x, unsigned short* __restrict__ xb,
    const int* __restrict__ Wq, const float* __restrict__ scale,
    const float* __restrict__ zero, const float* __restrict__ A,
    const float* __restrict__ Bm, unsigned short* __restrict__ Weff) {
  int t = threadIdx.x;
  if (blockIdx.x < 4096) {
    __shared__ float sA[64 * 17];
    __shared__ float sB[16 * 64];
    int bo = blockIdx.x >> 6;
    int bi = blockIdx.x & 63;
    int o0 = bo * 64, i0 = bi * 64;
    for (int j = t; j < 1024; j += 256) sA[(j >> 4) * 17 + (j & 15)] = A[i0 * 16 + j];
    for (int j = t; j < 1024; j += 256) sB[j] = Bm[(j >> 6) * N_DIM + o0 + (j & 63)];
    __syncthreads();
    for (int e = 0; e < 16; ++e) {
      int idx = e * 256 + t;
      int oo = idx >> 6, ii = idx & 63;
      int o = o0 + oo;
      float sc = scale[o * 64 + bi];
      float zp = zero[o * 64 + bi];
      float w = ((float)Wq[(size_t)o * K_DIM + i0 + ii] - zp) * sc;
      float acc = 0.f;
#pragma unroll
      for (int r = 0; r < 16; ++r) acc += sA[ii * 17 + r] * sB[r * 64 + oo];
      w += 2.0f * acc;
      Weff[(size_t)o * K_DIM + i0 + ii] = f2bf(w);
    }
  } else {
    int i = (blockIdx.x - 4096) * 256 + t;
    int stride = 2048 * 256;
    int n4 = (M_DIM * K_DIM) / 4;
    for (; i < n4; i += stride) {
      float4 v = reinterpret_cast<const float4*>(x)[i];
      ushort4 o;
      o.x = f2bf(v.x); o.y = f2bf(v.y); o.z = f2bf(v.z); o.w = f2bf(v.w);
      reinterpret_cast<ushort4*>(xb)[i] = o;
    }
  }
}

// ---------- 256x256 8-phase bf16 GEMM, 16x16x32 MFMA (R2 verified fragments) ----
#define BAR() __builtin_amdgcn_s_barrier()
#define SB()  __builtin_amdgcn_sched_barrier(0)
#define WAIT_LGKM() do { asm volatile("s_waitcnt lgkmcnt(0)" ::: "memory"); SB(); } while (0)
#define WAIT_VM6()  do { asm volatile("s_waitcnt vmcnt(6)" ::: "memory"); } while (0)

// swizzled LDS fragment read: region is [128][64] bf16 half-tile; 16B chunk c of
// row lives at physical column (c ^ (row&7)). Measured 0 bank conflicts (R2).
__device__ __forceinline__ bf16x8 lds_frag(const unsigned short* region, int row, int c) {
  return *reinterpret_cast<const bf16x8*>(region + row * 64 + ((c ^ (row & 7)) << 3));
}

__device__ __forceinline__ void readA(const unsigned short* reg, int mh, int lc, int lr,
                                      bf16x8 a[4][2]) {
#pragma unroll
  for (int m = 0; m < 4; ++m) {
    int row = mh * 64 + m * 16 + lc;
#pragma unroll
    for (int kk = 0; kk < 2; ++kk) a[m][kk] = lds_frag(reg, row, kk * 4 + lr);
  }
}

__device__ __forceinline__ void readB(const unsigned short* reg, int nh, int rB, int lc, int lr,
                                      bf16x8 b[2][2]) {
#pragma unroll
  for (int n = 0; n < 2; ++n) {
    int row = rB + (nh * 2 + n) * 16 + lc;
#pragma unroll
    for (int kk = 0; kk < 2; ++kk) b[n][kk] = lds_frag(reg, row, kk * 4 + lr);
  }
}

__device__ __forceinline__ void mfma_quad(const bf16x8 a[4][2], const bf16x8 b[2][2],
                                          f32x4 acc[8][4], int mh, int nh) {
  __builtin_amdgcn_s_setprio(1);
#pragma unroll
  for (int m = 0; m < 4; ++m)
#pragma unroll
    for (int n = 0; n < 2; ++n)
#pragma unroll
      for (int kk = 0; kk < 2; ++kk)
        acc[mh * 4 + m][nh * 2 + n] = __builtin_amdgcn_mfma_f32_16x16x32_bf16(
            a[m][kk], b[n][kk], acc[mh * 4 + m][nh * 2 + n], 0, 0, 0);
  __builtin_amdgcn_s_setprio(0);
}

__global__ __launch_bounds__(512, 2) void gemm_kernel(
    const unsigned short* __restrict__ xb, const unsigned short* __restrict__ wb,
    const float* __restrict__ bias, float* __restrict__ out) {
  // LDS: 2 bufs x [A0|A1|B0|B1], each region 128x64 bf16 (8192 ushort) = 128 KiB
  __shared__ unsigned short lds[65536];

  int bid = blockIdx.x;
  int swz = (bid & 7) * 64 + (bid >> 3);   // bijective: 512 % 8 == 0
  int mt = swz >> 4, nt = swz & 15;
  int m0 = mt * 256, n0 = nt * 256;

  int tid = threadIdx.x;
  int w = tid >> 6, lane = tid & 63;
  int wr = w >> 2, wc = w & 3;             // 2 x 4 waves; per-wave out = 128 x 64
  int lr = lane >> 4, lc = lane & 15;
  int rB = (wc & 1) * 64;

  // staging: chunk = l*512 + tid (16B units), row = chunk>>3, phys col = chunk&7,
  // logical (global) col = (chunk&7) ^ (row&7)  [inverse-swizzled source, linear dest]
  int r0 = tid >> 3, c0g = (tid & 7) ^ (r0 & 7);
  int ch1 = 512 + tid;
  int r1 = ch1 >> 3, c1g = (ch1 & 7) ^ (r1 & 7);
  int co0 = tid * 8, co1 = ch1 * 8;

  const unsigned short* sA[2][2];
  const unsigned short* sB[2][2];
  sA[0][0] = xb + (size_t)(m0 + r0) * K_DIM + c0g * 8;
  sA[0][1] = xb + (size_t)(m0 + r1) * K_DIM + c1g * 8;
  sA[1][0] = xb + (size_t)(m0 + 128 + r0) * K_DIM + c0g * 8;
  sA[1][1] = xb + (size_t)(m0 + 128 + r1) * K_DIM + c1g * 8;
  sB[0][0] = wb + (size_t)(n0 + r0) * K_DIM + c0g * 8;
  sB[0][1] = wb + (size_t)(n0 + r1) * K_DIM + c1g * 8;
  sB[1][0] = wb + (size_t)(n0 + 128 + r0) * K_DIM + c0g * 8;
  sB[1][1] = wb + (size_t)(n0 + 128 + r1) * K_DIM + c1g * 8;

#define STAGE_A(h, buf, kt) do { \
    async_copy16(sA[h][0] + (kt), &lds[(buf) * 32768 + (h) * 8192 + co0]); \
    async_copy16(sA[h][1] + (kt), &lds[(buf) * 32768 + (h) * 8192 + co1]); } while (0)
#define STAGE_B(h, buf, kt) do { \
    async_copy16(sB[h][0] + (kt), &lds[(buf) * 32768 + 16384 + (h) * 8192 + co0]); \
    async_copy16(sB[h][1] + (kt), &lds[(buf) * 32768 + 16384 + (h) * 8192 + co1]); } while (0)

  const unsigned short* aR[2] = { &lds[wr * 8192], &lds[32768 + wr * 8192] };
  const unsigned short* bR[2] = { &lds[16384 + (wc >> 1) * 8192],
                                  &lds[32768 + 16384 + (wc >> 1) * 8192] };

  f32x4 acc[8][4];
#pragma unroll
  for (int i = 0; i < 8; ++i)
#pragma unroll
    for (int j = 0; j < 4; ++j) acc[i][j] = f32x4{0.f, 0.f, 0.f, 0.f};

  // prologue: tile0 full, then tile1's B0,B1,A0 (A1 comes at P1)
  STAGE_A(0, 0, 0); STAGE_B(0, 0, 0); STAGE_B(1, 0, 0); STAGE_A(1, 0, 0);
  STAGE_B(0, 1, 64); STAGE_B(1, 1, 64); STAGE_A(0, 1, 64);
  WAIT_VM6(); BAR(); SB();   // oldest 8 loads (= tile0) landed

  bf16x8 a[4][2], b0[2][2], b1[2][2];

#pragma unroll 1
  for (int i = 0; i < 32; ++i) {
    int k1 = (2 * i + 1) * 64;             // tile t+1 (never wraps)
    int k2 = ((2 * i + 2) & 63) * 64;      // tile t+2 (wrap harmless at tail)
    int k3 = ((2 * i + 3) & 63) * 64;      // tile t+3

    // P1: Q(0,0) of tile t         stage Ah1(t+1)->buf1 (freed prev-P7)
    readA(aR[0], 0, lc, lr, a); readB(bR[0], 0, rB, lc, lr, b0);
    STAGE_A(1, 1, k1);
    SB(); BAR(); WAIT_LGKM();
    mfma_quad(a, b0, acc, 0, 0);
    SB(); BAR(); SB();
    // P2: Q(0,1)
    readB(bR[0], 1, rB, lc, lr, b1);
    SB(); BAR(); WAIT_LGKM();
    mfma_quad(a, b1, acc, 0, 1);
    SB(); BAR(); SB();
    // P3: Q(1,1)                   stage Bh0(t+2)->buf0 (B freed after P2)
    readA(aR[0], 1, lc, lr, a);
    STAGE_B(0, 0, k2);
    SB(); BAR(); WAIT_LGKM();
    mfma_quad(a, b1, acc, 1, 1);
    SB(); BAR(); SB();
    // P4: Q(1,0)                   stage Bh1,Ah0(t+2)->buf0 (A freed after P3)
    STAGE_B(1, 0, k2); STAGE_A(0, 0, k2);
    SB(); BAR();
    mfma_quad(a, b0, acc, 1, 0);
    SB(); WAIT_VM6(); BAR(); SB();   // full tile t+1 landed; 3 halves in flight
    // P5: Q(0,0) of tile t+1       stage Ah1(t+2)->buf0
    readA(aR[1], 0, lc, lr, a); readB(bR[1], 0, rB, lc, lr, b0);
    STAGE_A(1, 0, k2);
    SB(); BAR(); WAIT_LGKM();
    mfma_quad(a, b0, acc, 0, 0);
    SB(); BAR(); SB();
    // P6: Q(0,1)
    readB(bR[1], 1, rB, lc, lr, b1);
    SB(); BAR(); WAIT_LGKM();
    mfma_quad(a, b1, acc, 0, 1);
    SB(); BAR(); SB();
    // P7: Q(1,1)                   stage Bh0(t+3)->buf1 (B freed after P6)
    readA(aR[1], 1, lc, lr, a);
    STAGE_B(0, 1, k3);
    SB(); BAR(); WAIT_LGKM();
    mfma_quad(a, b1, acc, 1, 1);
    SB(); BAR(); SB();
    // P8: Q(1,0)                   stage Bh1,Ah0(t+3)->buf1 (A freed after P7)
    STAGE_B(1, 1, k3); STAGE_A(0, 1, k3);
    SB(); BAR();
    mfma_quad(a, b0, acc, 1, 0);
    SB(); WAIT_VM6(); BAR(); SB();   // full tile t+2 landed; 3 halves in flight
  }
  asm volatile("s_waitcnt vmcnt(0)" ::: "memory");  // drain stray tail prefetches

  // epilogue: 16x16 C/D layout col=lane&15, row=(lane>>4)*4+j  [m89/m91]
#pragma unroll
  for (int ni = 0; ni < 4; ++ni) {
    int n = n0 + wc * 64 + ni * 16 + lc;
    float bv = bias[n];
#pragma unroll
    for (int mi = 0; mi < 8; ++mi) {
      int mb = m0 + wr * 128 + mi * 16 + lr * 4;
#pragma unroll
      for (int j = 0; j < 4; ++j)
        out[(size_t)(mb + j) * N_DIM + n] = acc[mi][ni][j] + bv;
    }
  }
#undef STAGE_A
#undef STAGE_B
}

extern "C" void kernel_launch(void* const* d_in, const int* in_sizes, int n_in,
                              void* d_out, int out_size, void* d_ws, size_t ws_size,
                              hipStream_t stream) {
  const float* x     = (const float*)d_in[0];
  const int*   Wq    = (const int*)d_in[1];
  const float* scale = (const float*)d_in[2];
  const float* zero  = (const float*)d_in[3];
  const float* lA    = (const float*)d_in[4];
  const float* lB    = (const float*)d_in[5];
  const float* bias  = (const float*)d_in[6];
  float* out = (float*)d_out;

  unsigned short* xb = (unsigned short*)d_ws;                                      // 64 MB
  unsigned short* wb = (unsigned short*)((char*)d_ws + (size_t)M_DIM * K_DIM * 2); // +32 MB

  prep_kernel<<<6144, 256, 0, stream>>>(x, xb, Wq, scale, zero, lA, lB, wb);
  gemm_kernel<<<512, 512, 0, stream>>>(xb, wb, bias, out);
}

// Round 5
// 311.527 us; speedup vs baseline: 1.1241x; 1.0266x over previous
//
#include <hip/hip_runtime.h>
#include <hip/hip_bf16.h>
#include <stdint.h>

#define M_DIM 8192
#define N_DIM 4096
#define K_DIM 4096

typedef __attribute__((ext_vector_type(8))) __bf16 bf16x8;
typedef __attribute__((ext_vector_type(4))) float f32x4;

__device__ inline unsigned short f2bf(float f) {
  unsigned u = __builtin_bit_cast(unsigned, f);
  u += 0x7FFF + ((u >> 16) & 1);   // round-to-nearest-even
  return (unsigned short)(u >> 16);
}

__device__ inline void async_copy16(const void* g, void* l) {
  __builtin_amdgcn_global_load_lds(
      (const __attribute__((address_space(1))) unsigned int*)g,
      (__attribute__((address_space(3))) unsigned int*)l, 16, 0, 0);
}

// ---------- fused prep: blocks [0,4096) build W_eff; [4096,6144) cvt x ----------
__global__ __launch_bounds__(256) void prep_kernel(
    const float* __restrict__ x, unsigned short* __restrict__ xb,
    const int* __restrict__ Wq, const float* __restrict__ scale,
    const float* __restrict__ zero, const float* __restrict__ A,
    const float* __restrict__ Bm, unsigned short* __restrict__ Weff) {
  int t = threadIdx.x;
  if (blockIdx.x < 4096) {
    __shared__ float sA[64 * 17];
    __shared__ float sB[16 * 64];
    int bo = blockIdx.x >> 6;
    int bi = blockIdx.x & 63;
    int o0 = bo * 64, i0 = bi * 64;
    for (int j = t; j < 1024; j += 256) sA[(j >> 4) * 17 + (j & 15)] = A[i0 * 16 + j];
    for (int j = t; j < 1024; j += 256) sB[j] = Bm[(j >> 6) * N_DIM + o0 + (j & 63)];
    __syncthreads();
    for (int e = 0; e < 16; ++e) {
      int idx = e * 256 + t;
      int oo = idx >> 6, ii = idx & 63;
      int o = o0 + oo;
      float sc = scale[o * 64 + bi];
      float zp = zero[o * 64 + bi];
      float w = ((float)Wq[(size_t)o * K_DIM + i0 + ii] - zp) * sc;
      float acc = 0.f;
#pragma unroll
      for (int r = 0; r < 16; ++r) acc += sA[ii * 17 + r] * sB[r * 64 + oo];
      w += 2.0f * acc;
      Weff[(size_t)o * K_DIM + i0 + ii] = f2bf(w);
    }
  } else {
    int i = (blockIdx.x - 4096) * 256 + t;
    int stride = 2048 * 256;
    int n4 = (M_DIM * K_DIM) / 4;
    for (; i < n4; i += stride) {
      float4 v = reinterpret_cast<const float4*>(x)[i];
      ushort4 o;
      o.x = f2bf(v.x); o.y = f2bf(v.y); o.z = f2bf(v.z); o.w = f2bf(v.w);
      reinterpret_cast<ushort4*>(xb)[i] = o;
    }
  }
}

// ---------- 256x256 8-phase bf16 GEMM, 1-phase register read-ahead ----------
#define BAR() __builtin_amdgcn_s_barrier()
#define SB()  __builtin_amdgcn_sched_barrier(0)
#define WAIT_VM2() do { asm volatile("s_waitcnt vmcnt(2)" ::: "memory"); } while (0)

// swizzled LDS fragment read: region is [128][64] bf16 half-tile; 16B chunk c of
// row lives at physical column (c ^ (row&7)). Measured 0 bank conflicts (R2/R4).
__device__ __forceinline__ bf16x8 lds_frag(const unsigned short* region, int row, int c) {
  return *reinterpret_cast<const bf16x8*>(region + row * 64 + ((c ^ (row & 7)) << 3));
}

__device__ __forceinline__ void readA(const unsigned short* reg, int mh, int lc, int lr,
                                      bf16x8 a[4][2]) {
#pragma unroll
  for (int m = 0; m < 4; ++m) {
    int row = mh * 64 + m * 16 + lc;
#pragma unroll
    for (int kk = 0; kk < 2; ++kk) a[m][kk] = lds_frag(reg, row, kk * 4 + lr);
  }
}

__device__ __forceinline__ void readB(const unsigned short* reg, int nh, int rB, int lc, int lr,
                                      bf16x8 b[2][2]) {
#pragma unroll
  for (int n = 0; n < 2; ++n) {
    int row = rB + (nh * 2 + n) * 16 + lc;
#pragma unroll
    for (int kk = 0; kk < 2; ++kk) b[n][kk] = lds_frag(reg, row, kk * 4 + lr);
  }
}

__device__ __forceinline__ void mfma_quad(const bf16x8 a[4][2], const bf16x8 b[2][2],
                                          f32x4 acc[8][4], int mh, int nh) {
  __builtin_amdgcn_s_setprio(1);
#pragma unroll
  for (int m = 0; m < 4; ++m)
#pragma unroll
    for (int n = 0; n < 2; ++n)
#pragma unroll
      for (int kk = 0; kk < 2; ++kk)
        acc[mh * 4 + m][nh * 2 + n] = __builtin_amdgcn_mfma_f32_16x16x32_bf16(
            a[m][kk], b[n][kk], acc[mh * 4 + m][nh * 2 + n], 0, 0, 0);
  __builtin_amdgcn_s_setprio(0);
}

__global__ __launch_bounds__(512, 2) void gemm_kernel(
    const unsigned short* __restrict__ xb, const unsigned short* __restrict__ wb,
    const float* __restrict__ bias, float* __restrict__ out) {
  // LDS: 2 bufs x [A0|A1|B0|B1], each region 128x64 bf16 (8192 ushort) = 128 KiB
  __shared__ unsigned short lds[65536];

  int bid = blockIdx.x;
  int swz = (bid & 7) * 64 + (bid >> 3);   // bijective: 512 % 8 == 0
  int mt = swz >> 4, nt = swz & 15;
  int m0 = mt * 256, n0 = nt * 256;

  int tid = threadIdx.x;
  int w = tid >> 6, lane = tid & 63;
  int wr = w >> 2, wc = w & 3;             // 2 x 4 waves; per-wave out = 128 x 64
  int lr = lane >> 4, lc = lane & 15;
  int rB = (wc & 1) * 64;

  // staging: chunk = l*512 + tid (16B units), row = chunk>>3, phys col = chunk&7,
  // logical (global) col = (chunk&7) ^ (row&7). Row+64 keeps the same swizzle.
  int r0 = tid >> 3, c0g = (tid & 7) ^ (r0 & 7);
  int co0 = tid * 8, co1 = (512 + tid) * 8;

  const unsigned short* sA00 = xb + (size_t)(m0 + r0) * K_DIM + c0g * 8;
  const unsigned short* sB00 = wb + (size_t)(n0 + r0) * K_DIM + c0g * 8;

#define STAGE_A(h, buf, kt) do { \
    const unsigned short* _p = sA00 + (size_t)(h) * 128 * K_DIM + (size_t)(kt); \
    async_copy16(_p, &lds[(buf) * 32768 + (h) * 8192 + co0]); \
    async_copy16(_p + (size_t)64 * K_DIM, &lds[(buf) * 32768 + (h) * 8192 + co1]); } while (0)
#define STAGE_B(h, buf, kt) do { \
    const unsigned short* _p = sB00 + (size_t)(h) * 128 * K_DIM + (size_t)(kt); \
    async_copy16(_p, &lds[(buf) * 32768 + 16384 + (h) * 8192 + co0]); \
    async_copy16(_p + (size_t)64 * K_DIM, &lds[(buf) * 32768 + 16384 + (h) * 8192 + co1]); } while (0)

  const unsigned short* aR[2] = { &lds[wr * 8192], &lds[32768 + wr * 8192] };
  const unsigned short* bR[2] = { &lds[16384 + (wc >> 1) * 8192],
                                  &lds[32768 + 16384 + (wc >> 1) * 8192] };

  f32x4 acc[8][4];
#pragma unroll
  for (int i = 0; i < 8; ++i)
#pragma unroll
    for (int j = 0; j < 4; ++j) acc[i][j] = f32x4{0.f, 0.f, 0.f, 0.f};

  // prologue: tile0 (8 loads, oldest), then tile1's Bh0 + Bh1,Ah0 (6 loads)
  STAGE_B(0, 0, 0); STAGE_B(1, 0, 0); STAGE_A(0, 0, 0); STAGE_A(1, 0, 0);
  STAGE_B(0, 1, 64);
  STAGE_B(1, 1, 64); STAGE_A(0, 1, 64);
  asm volatile("s_waitcnt vmcnt(6)" ::: "memory");   // tile0 fully landed
  BAR(); SB();

  bf16x8 aU[4][2], aV[4][2], b0[2][2], b1[2][2];
  // pre-read P1 fragments: A0h0 -> aU, B0h0 -> b0
  readA(aR[0], 0, lc, lr, aU); readB(bR[0], 0, rB, lc, lr, b0);
  SB();

#pragma unroll 1
  for (int i = 0; i < 32; ++i) {
    int k1 = (2 * i + 1) * 64;             // tile t+1 (never wraps)
    int k2 = ((2 * i + 2) & 63) * 64;      // tile t+2 (wrap harmless at tail)
    int k3 = ((2 * i + 3) & 63) * 64;      // tile t+3

    // ---- P1: MFMA Q(0,0)=aU,b0   read(P2): B0h1->b1   stage Ah1(t+1)->buf1
    readB(bR[0], 1, rB, lc, lr, b1);
    SB(); STAGE_A(1, 1, k1); SB();
    mfma_quad(aU, b0, acc, 0, 0);
    SB(); BAR(); SB();
    // ---- P2: Q(0,1)=aU,b1        read(P3): A0h1->aV
    readA(aR[0], 1, lc, lr, aV);
    SB();
    mfma_quad(aU, b1, acc, 0, 1);
    SB(); BAR(); SB();
    // ---- P3: Q(1,0)=aV,b0        stage Bh0(t+2)->buf0    [seam: t+1 landed]
    SB(); STAGE_B(0, 0, k2); SB();
    mfma_quad(aV, b0, acc, 1, 0);
    SB(); WAIT_VM2(); BAR(); SB();
    // ---- P4: Q(1,1)=aV,b1        read(P5): A1h0->aU, B1h0->b0
    //                              stage Bh1,Ah0(t+2)->buf0
    readA(aR[1], 0, lc, lr, aU); readB(bR[1], 0, rB, lc, lr, b0);
    SB(); STAGE_B(1, 0, k2); STAGE_A(0, 0, k2); SB();
    mfma_quad(aV, b1, acc, 1, 1);
    SB(); BAR(); SB();
    // ---- P5: Q(0,0)=aU,b0        read(P6): B1h1->b1      stage Ah1(t+2)->buf0
    readB(bR[1], 1, rB, lc, lr, b1);
    SB(); STAGE_A(1, 0, k2); SB();
    mfma_quad(aU, b0, acc, 0, 0);
    SB(); BAR(); SB();
    // ---- P6: Q(0,1)=aU,b1        read(P7): A1h1->aV
    readA(aR[1], 1, lc, lr, aV);
    SB();
    mfma_quad(aU, b1, acc, 0, 1);
    SB(); BAR(); SB();
    // ---- P7: Q(1,0)=aV,b0        stage Bh0(t+3)->buf1    [seam: t+2 landed]
    SB(); STAGE_B(0, 1, k3); SB();
    mfma_quad(aV, b0, acc, 1, 0);
    SB(); WAIT_VM2(); BAR(); SB();
    // ---- P8: Q(1,1)=aV,b1        read(P1'): A0h0->aU, B0h0->b0 (tile t+2)
    //                              stage Bh1,Ah0(t+3)->buf1
    readA(aR[0], 0, lc, lr, aU); readB(bR[0], 0, rB, lc, lr, b0);
    SB(); STAGE_B(1, 1, k3); STAGE_A(0, 1, k3); SB();
    mfma_quad(aV, b1, acc, 1, 1);
    SB(); BAR(); SB();
  }
  asm volatile("s_waitcnt vmcnt(0) lgkmcnt(0)" ::: "memory");  // drain strays

  // epilogue: 16x16 C/D layout col=lane&15, row=(lane>>4)*4+j  [m89/m91]
#pragma unroll
  for (int ni = 0; ni < 4; ++ni) {
    int n = n0 + wc * 64 + ni * 16 + lc;
    float bv = bias[n];
#pragma unroll
    for (int mi = 0; mi < 8; ++mi) {
      int mb = m0 + wr * 128 + mi * 16 + lr * 4;
#pragma unroll
      for (int j = 0; j < 4; ++j)
        out[(size_t)(mb + j) * N_DIM + n] = acc[mi][ni][j] + bv;
    }
  }
#undef STAGE_A
#undef STAGE_B
}

extern "C" void kernel_launch(void* const* d_in, const int* in_sizes, int n_in,
                              void* d_out, int out_size, void* d_ws, size_t ws_size,
                              hipStream_t stream) {
  const float* x     = (const float*)d_in[0];
  const int*   Wq    = (const int*)d_in[1];
  const float* scale = (const float*)d_in[2];
  const float* zero  = (const float*)d_in[3];
  const float* lA    = (const float*)d_in[4];
  const float* lB    = (const float*)d_in[5];
  const float* bias  = (const float*)d_in[6];
  float* out = (float*)d_out;

  unsigned short* xb = (unsigned short*)d_ws;                                      // 64 MB
  unsigned short* wb = (unsigned short*)((char*)d_ws + (size_t)M_DIM * K_DIM * 2); // +32 MB

  prep_kernel<<<6144, 256, 0, stream>>>(x, xb, Wq, scale, zero, lA, lB, wb);
  gemm_kernel<<<512, 512, 0, stream>>>(xb, wb, bias, out);
}